// Round 9
// baseline (313.892 us; speedup 1.0000x reference)
//
#include <hip/hip_runtime.h>
#include <hip/hip_bf16.h>
#include <cstddef>

// Problem constants
#define NB 256   // batch
#define RR 32    // rooms
#define WW 8     // room width
#define HH 6     // room height
#define MXY 72   // map extent
#define EMB 6
#define CIN1 16  // 9 + 1 + 6

typedef __bf16 bf16x8 __attribute__((ext_vector_type(8)));
typedef float floatx4 __attribute__((ext_vector_type(4)));

// --- Workspace layout (byte offsets) ---------------------------------------
// Conv weights packed per-kstep (2KB per kstep per ntile-group layout):
//   W1F: 13+1 ksteps [0,57344) ; W2F: 18 [57344,131072) ; W3F: 18 [131072,..)
static const size_t B_W1F  = 0;
static const size_t B_W2F  = 57344;
static const size_t B_W3F  = 131072;
static const size_t B_RAUX = 204800;    // room masks (32 u64)
static const size_t B_RINV = 205056;    // 1/room_size (32 f32)
static const size_t B_HEAD = 205312;    // fp32 head weights, 122880 floats
static const size_t F_WR1T = 0;         // (64,128)
static const size_t F_WR2T = 8192;      // (128,128)
static const size_t F_F1T  = 24576;     // (128,256)
static const size_t F_F2T  = 57344;     // (256,256)
static const size_t B_FEAT = 696832;    // (256,32,64) f32 = 2 MB
static const size_t B_IMSK = 2793984;   // (256,32) u32 intersect masks (32 KB)

__device__ inline short f2b(float f) {
    unsigned u = __builtin_bit_cast(unsigned, f);
    unsigned r = (u + 0x7fffu + ((u >> 16) & 1u)) >> 16;
    return (short)r;
}

// ---------------------------------------------------------------------------
// ONE merged prep kernel (round 9: was 3 launches; ~10us launch overhead each
// dominates these tiny kernels). Disjoint index ranges:
//   [0, 225280)        weights -> bf16 B-frag order + head transposes
//   [225280, 233472)   per-(sample,room) 32-bit intersect masks
//   [233472, 233536)   room footprint bitmasks + 1/room_size
// Fragment order: [kk][ntile][lane][j] ; virtual k = kk*32 + (lane>>4)*8 + j
// oc = ntile*16 + (lane&15).
// conv1: (tap,ci) natural. conv2/3: position cp -> channel (cp>>2)+(cp&3)*16
// (paired-channel layout Y1/Y2 are written in).
// ---------------------------------------------------------------------------
__global__ void prep_all(const float* __restrict__ w1, const float* __restrict__ w2,
                         const float* __restrict__ w3, const float* __restrict__ wr1,
                         const float* __restrict__ wr2, const float* __restrict__ wf1,
                         const float* __restrict__ wf2, const float* __restrict__ rt,
                         const int* __restrict__ pos, char* __restrict__ ws)
{
    short* W1F = (short*)(ws + B_W1F);
    short* W2F = (short*)(ws + B_W2F);
    short* W3F = (short*)(ws + B_W3F);
    float* HEAD = (float*)(ws + B_HEAD);

    int idx = blockIdx.x * 256 + threadIdx.x;
    if (idx < 28672) {  // conv1: 14 ksteps (padded), CIN=16, taps 0..24 real
        int j = idx & 7, lane = (idx >> 3) & 63, nt = (idx >> 9) & 3, kk = idx >> 11;
        int k = kk * 32 + (lane >> 4) * 8 + j;
        int oc = nt * 16 + (lane & 15);
        int tap = k >> 4, ci = k & 15;
        float v = (tap < 25) ? w1[(oc * 16 + ci) * 25 + tap] : 0.f;
        W1F[idx] = f2b(v);
        return;
    }
    idx -= 28672;
    if (idx < 36864) {  // conv2: 18 ksteps, CIN=64, 9 taps, permuted ci
        int j = idx & 7, lane = (idx >> 3) & 63, nt = (idx >> 9) & 3, kk = idx >> 11;
        int k = kk * 32 + (lane >> 4) * 8 + j;
        int oc = nt * 16 + (lane & 15);
        int tap = k >> 6, cp = k & 63;
        int ci = (cp >> 2) + (cp & 3) * 16;
        W2F[idx] = f2b(w2[(oc * 64 + ci) * 9 + tap]);
        return;
    }
    idx -= 36864;
    if (idx < 36864) {  // conv3, permuted ci
        int j = idx & 7, lane = (idx >> 3) & 63, nt = (idx >> 9) & 3, kk = idx >> 11;
        int k = kk * 32 + (lane >> 4) * 8 + j;
        int oc = nt * 16 + (lane & 15);
        int tap = k >> 6, cp = k & 63;
        int ci = (cp >> 2) + (cp & 3) * 16;
        W3F[idx] = f2b(w3[(oc * 64 + ci) * 9 + tap]);
        return;
    }
    idx -= 36864;
    if (idx < 8192)  { int o = idx & 127, c = idx >> 7; HEAD[F_WR1T + idx] = wr1[o * 64 + c]; return; }
    idx -= 8192;
    if (idx < 16384) { int o = idx & 127, c = idx >> 7; HEAD[F_WR2T + idx] = wr2[o * 128 + c]; return; }
    idx -= 16384;
    if (idx < 32768) { int o = idx & 255, c = idx >> 8; HEAD[F_F1T + idx] = wf1[o * 128 + c]; return; }
    idx -= 32768;
    if (idx < 65536) { int o = idx & 255, c = idx >> 8; HEAD[F_F2T + idx] = wf2[o * 256 + c]; return; }
    idx -= 65536;
    if (idx < 8192) {  // intersect masks: rooms touching the 16x14 X halo tile
        const int n = idx >> 5, r0 = idx & 31;
        const int px0 = pos[(n * RR + r0) * 2 + 0];
        const int py0 = pos[(n * RR + r0) * 2 + 1];
        unsigned m = 0;
        for (int r = 0; r < RR; ++r) {
            int rpx = pos[(n * RR + r) * 2 + 0];
            int rpy = pos[(n * RR + r) * 2 + 1];
            if (rpx >= px0 - 11 && rpx <= px0 + 11 && rpy >= py0 - 9 && rpy <= py0 + 9)
                m |= 1u << r;
        }
        ((unsigned*)(ws + B_IMSK))[n * RR + r0] = m;
        return;
    }
    idx -= 8192;
    if (idx < RR) {  // room footprint bitmasks (48 bits) + 1/room_size
        unsigned long long m = 0ull;
        int cnt = 0;
        for (int j = 0; j < WW * HH; ++j)
            if (rt[idx * 9 * 48 + j] != 0.f) { m |= (1ull << j); ++cnt; }
        ((unsigned long long*)(ws + B_RAUX))[idx] = m;
        ((float*)(ws + B_RINV))[idx] = 1.f / (float)cnt;
    }
}

// ---------------------------------------------------------------------------
// ROUND-9 FUSED CONV CHAIN — occupancy push to 5 blocks/CU.
//
// Round-8 pipe accounting (per CU): MFMA 28%, LDS 38% (incl. conflicts),
// VALU 25% — no pipe saturated -> latency-bound. Coverage arithmetic: per
// kstep a wave has ~39cy MFMA to hide ~120cy ds_read + ~200cy B-load; at
// 3.4 blk/CU the product (~134cy) is marginally short. LDS (29.2KB) allows
// 5 blocks; only the round-7 safety bound (256,4) capped us. Live set is now
// 56 arch + ~32 acc ~= 88 <= 102 (round 7 removed the B4b ping-pong that
// caused round 6's spill), so (256,5) fits. Tripwire: WRITE_SIZE ~2MB; if
// it balloons the allocator spilled -> revert to (256,4).
//
// X built in-kernel (round 8); conv body otherwise identical to round 7.
// ---------------------------------------------------------------------------
__global__ __launch_bounds__(256, 5) void fused_conv(
    const unsigned* __restrict__ imask, const float* __restrict__ rt,
    const float* __restrict__ emb, const short* __restrict__ wAll,
    const float* __restrict__ bc1, const float* __restrict__ bc2,
    const float* __restrict__ bc3, const int* __restrict__ pos,
    const unsigned long long* __restrict__ rmask, float* __restrict__ feat)
{
    __shared__ __align__(16) short s_Y1[120 * 72];  // 17280 B, paired-channel
    __shared__ __align__(16) short s_u[80 * 72];    // X[224][24] then Y2[80][72]
    __shared__ float s_feat[64];

    const int tid = threadIdx.x;
    const int lane = tid & 63;
    const int wv = tid >> 6;
    const int ml = lane & 15;
    const int q = lane >> 4;
    const int room = blockIdx.x;
    const int n = blockIdx.y;

    const int px = pos[(n * RR + room) * 2 + 0];
    const int py = pos[(n * RR + room) * 2 + 1];

    const short* W1F = wAll;
    const short* W2F = wAll + B_W2F / 2;
    const short* W3F = wAll + B_W3F / 2;

    bf16x8 Bb[2][4];
    auto load_k = [&](const short* wF, int kk, bf16x8* dst) {
        const short* src = wF + (size_t)kk * 2048;
#pragma unroll
        for (int j2 = 0; j2 < 4; ++j2)
            dst[j2] = *reinterpret_cast<const bf16x8*>(src + (j2 * 64 + lane) * 8);
    };

    load_k(W1F, 0, Bb[0]);

    // ---- build X tile in-kernel: threads 0..223, one 16-channel pixel ----
    {
        const unsigned mk0 = imask[n * RR + room];  // uniform
        if (tid < 224) {
            const int row = tid / 14, col = tid - (tid / 14) * 14;
            const int gx = px - 4 + row, gy = py - 4 + col;
            float a[16];
#pragma unroll
            for (int c = 0; c < 16; ++c) a[c] = 0.f;
            a[9] = ((unsigned)gx < (unsigned)MXY && (unsigned)gy < (unsigned)MXY) ? 1.f : 0.f;

            unsigned mm = mk0;
            while (mm) {
                const int r = __builtin_ctz(mm);
                mm &= mm - 1;
                const int rpx = pos[(n * RR + r) * 2 + 0];  // uniform -> s_load
                const int rpy = pos[(n * RR + r) * 2 + 1];
                const int w = gx - rpx, h = gy - rpy;
                if ((unsigned)w < (unsigned)WW && (unsigned)h < (unsigned)HH) {
                    const int j = w * HH + h;
                    const float* rr = rt + r * 9 * 48;
#pragma unroll
                    for (int c = 0; c < 9; ++c) a[c] += rr[c * 48 + j];
                    const float mv = rr[j];  // channel 0 = room_map
#pragma unroll
                    for (int e = 0; e < EMB; ++e) a[10 + e] += emb[r * EMB + e] * mv;
                }
            }
            short o[16];
#pragma unroll
            for (int c = 0; c < 16; ++c) o[c] = f2b(a[c]);
            *reinterpret_cast<uint4*>(&s_u[tid * 24 + 0]) = *reinterpret_cast<uint4*>(o);
            *reinterpret_cast<uint4*>(&s_u[tid * 24 + 8]) = *reinterpret_cast<uint4*>(o + 8);
        }
    }
    __syncthreads();  // barrier 1: X staged

    // ================= conv1: 5x5, X(16ch) -> Y1 12x10x64 =================
    {
        int prow[2], pcol[2];
#pragma unroll
        for (int i = 0; i < 2; ++i) {
            int p = wv * 32 + i * 16 + ml;
            if (p > 119) p = 119;  // pad px: duplicate compute, discarded
            prow[i] = p / 10; pcol[i] = p - prow[i] * 10;
        }
        floatx4 acc1[2][4] = {};

#pragma unroll
        for (int kk = 0; kk < 13; ++kk) {  // taps 0..25 (25 zero-padded)
            if (kk < 12) load_k(W1F, kk + 1, Bb[(kk + 1) & 1]);
            else         load_k(W2F, 0, Bb[1]);  // chain prefetch into conv2
            int tap = kk * 2 + (q >> 1);
            if (tap > 24) tap = 24;  // k-slots past tap24 have zero weights
            int chb = (q & 1) * 8;
            int dx = tap / 5, dy = tap - dx * 5;
            __builtin_amdgcn_s_setprio(1);
#pragma unroll
            for (int i = 0; i < 2; ++i) {
                bf16x8 A = *reinterpret_cast<const bf16x8*>(
                    &s_u[((prow[i] + dx) * 14 + (pcol[i] + dy)) * 24 + chb]);
#pragma unroll
                for (int j2 = 0; j2 < 4; ++j2)
                    acc1[i][j2] = __builtin_amdgcn_mfma_f32_16x16x32_bf16(
                        A, Bb[kk & 1][j2], acc1[i][j2], 0, 0, 0);
            }
            __builtin_amdgcn_s_setprio(0);
        }
        // epilogue: bias + relu, b64 paired-channel stores
        float b4[4];
#pragma unroll
        for (int j2 = 0; j2 < 4; ++j2) b4[j2] = bc1[j2 * 16 + ml];
#pragma unroll
        for (int i = 0; i < 2; ++i)
#pragma unroll
            for (int r = 0; r < 4; ++r) {
                int p = wv * 32 + i * 16 + q * 4 + r;
                if (p < 120) {
                    unsigned lo = (unsigned)(unsigned short)f2b(fmaxf(acc1[i][0][r] + b4[0], 0.f))
                                | ((unsigned)(unsigned short)f2b(fmaxf(acc1[i][1][r] + b4[1], 0.f)) << 16);
                    unsigned hi = (unsigned)(unsigned short)f2b(fmaxf(acc1[i][2][r] + b4[2], 0.f))
                                | ((unsigned)(unsigned short)f2b(fmaxf(acc1[i][3][r] + b4[3], 0.f)) << 16);
                    *reinterpret_cast<uint2*>(&s_Y1[p * 72 + ml * 4]) = make_uint2(lo, hi);
                }
            }
    }
    __syncthreads();  // barrier 2: Y1 complete; X dead

    // ===== conv2: 3x3, Y1 -> Y2 10x8x64 (tiles 0-3 owned, tile 4 n-split) ==
    {
        int prowA, pcolA, prowB, pcolB;
        {
            int p0 = wv * 16 + ml; prowA = p0 >> 3; pcolA = p0 & 7;
            int p1 = 64 + ml;      prowB = p1 >> 3; pcolB = p1 & 7;
        }
        floatx4 acc2[4] = {};
        floatx4 acc2s = {};

#pragma unroll
        for (int kk = 0; kk < 18; ++kk) {
            if (kk < 17) load_k(W2F, kk + 1, Bb[kk & 1]);
            else         load_k(W3F, 0, Bb[1]);  // chain prefetch into conv3
            // n-split tile's B frag: direct per-kstep load (L1-resident),
            // wave-uniform base (rule #20 safe), no ping-pong liveness.
            bf16x8 B4 = *reinterpret_cast<const bf16x8*>(
                W2F + (size_t)kk * 2048 + (wv * 64 + lane) * 8);
            const int tap = kk >> 1;
            const int chb = (kk & 1) * 32 + q * 8;
            const int dx = tap / 3, dy = tap - (tap / 3) * 3;
            bf16x8 A0 = *reinterpret_cast<const bf16x8*>(
                &s_Y1[((prowA + dx) * 10 + (pcolA + dy)) * 72 + chb]);
            bf16x8 A4 = *reinterpret_cast<const bf16x8*>(
                &s_Y1[((prowB + dx) * 10 + (pcolB + dy)) * 72 + chb]);
            __builtin_amdgcn_s_setprio(1);
#pragma unroll
            for (int j2 = 0; j2 < 4; ++j2)
                acc2[j2] = __builtin_amdgcn_mfma_f32_16x16x32_bf16(A0, Bb[(kk + 1) & 1][j2], acc2[j2], 0, 0, 0);
            acc2s = __builtin_amdgcn_mfma_f32_16x16x32_bf16(A4, B4, acc2s, 0, 0, 0);
            __builtin_amdgcn_s_setprio(0);
        }
        // epilogue into s_u (X dead): own tile b64, shared tile scalar
        float b4[4];
#pragma unroll
        for (int j2 = 0; j2 < 4; ++j2) b4[j2] = bc2[j2 * 16 + ml];
#pragma unroll
        for (int r = 0; r < 4; ++r) {
            int p = wv * 16 + q * 4 + r;
            unsigned lo = (unsigned)(unsigned short)f2b(fmaxf(acc2[0][r] + b4[0], 0.f))
                        | ((unsigned)(unsigned short)f2b(fmaxf(acc2[1][r] + b4[1], 0.f)) << 16);
            unsigned hi = (unsigned)(unsigned short)f2b(fmaxf(acc2[2][r] + b4[2], 0.f))
                        | ((unsigned)(unsigned short)f2b(fmaxf(acc2[3][r] + b4[3], 0.f)) << 16);
            *reinterpret_cast<uint2*>(&s_u[p * 72 + ml * 4]) = make_uint2(lo, hi);
        }
        {
            float bt = bc2[wv * 16 + ml];
#pragma unroll
            for (int r = 0; r < 4; ++r) {
                int p = 64 + q * 4 + r;
                s_u[p * 72 + ml * 4 + wv] = f2b(fmaxf(acc2s[r] + bt, 0.f));
            }
        }
        if (tid < 64) s_feat[tid] = 0.f;
    }
    __syncthreads();  // barrier 3: Y2 complete

    // ====== conv3: 3x3, Y2 -> 8x6 masked room-sum (waves 0-2) ======
    if (wv < 3) {
        int p0 = wv * 16 + ml;
        int row3 = p0 / 6, col3 = p0 - (p0 / 6) * 6;
        floatx4 acc3[4] = {};

#pragma unroll
        for (int kk = 0; kk < 18; ++kk) {
            if (kk < 17) load_k(W3F, kk + 1, Bb[kk & 1]);
            const int tap = kk >> 1;
            const int chb = (kk & 1) * 32 + q * 8;
            const int dx = tap / 3, dy = tap - (tap / 3) * 3;
            bf16x8 A = *reinterpret_cast<const bf16x8*>(
                &s_u[((row3 + dx) * 8 + (col3 + dy)) * 72 + chb]);
            __builtin_amdgcn_s_setprio(1);
#pragma unroll
            for (int j2 = 0; j2 < 4; ++j2)
                acc3[j2] = __builtin_amdgcn_mfma_f32_16x16x32_bf16(A, Bb[(kk + 1) & 1][j2], acc3[j2], 0, 0, 0);
            __builtin_amdgcn_s_setprio(0);
        }
        float b4[4];
#pragma unroll
        for (int j2 = 0; j2 < 4; ++j2) b4[j2] = bc3[j2 * 16 + ml];
        float part[4] = {0.f, 0.f, 0.f, 0.f};
        const unsigned long long mk = rmask[room];
#pragma unroll
        for (int r = 0; r < 4; ++r) {
            int p = wv * 16 + q * 4 + r;  // == w*6+h == mask bit index
            if ((mk >> p) & 1ull) {
#pragma unroll
                for (int j2 = 0; j2 < 4; ++j2)
                    part[j2] += fmaxf(acc3[j2][r] + b4[j2], 0.f);
            }
        }
#pragma unroll
        for (int j2 = 0; j2 < 4; ++j2) {
            part[j2] += __shfl_xor(part[j2], 16);
            part[j2] += __shfl_xor(part[j2], 32);
        }
        if (q == 0) {
#pragma unroll
            for (int j2 = 0; j2 < 4; ++j2)
                atomicAdd(&s_feat[j2 * 16 + ml], part[j2]);  // 3 contenders
        }
    }
    __syncthreads();  // barrier 4
    if (tid < 64)
        feat[((size_t)n * RR + room) * 64 + tid] = s_feat[tid];
}

// ---------------------------------------------------------------------------
// Per-sample head: room MLP (64->128->128), room-sum, fc1, fc2.
// FEAT holds unnormalized masked sums; normalize by rinv here.
// ---------------------------------------------------------------------------
__global__ __launch_bounds__(256) void mlp_head(const float* __restrict__ feat,
                                                const float* __restrict__ HEAD,
                                                const float* __restrict__ rinv,
                                                const float* __restrict__ b1,
                                                const float* __restrict__ b2,
                                                const float* __restrict__ bf1,
                                                const float* __restrict__ bf2,
                                                float* __restrict__ outp)
{
    __shared__ __align__(16) float s_feat[RR * 64];
    __shared__ __align__(16) float s_h1[RR * 128];
    __shared__ __align__(16) float s_s[2 * 128];
    __shared__ __align__(16) float s_sf[128];
    __shared__ __align__(16) float s_t1[256];

    const int n = blockIdx.x;
    const int tid = threadIdx.x;
    const float* W1t = HEAD + F_WR1T;
    const float* W2t = HEAD + F_WR2T;
    const float* F1t = HEAD + F_F1T;
    const float* F2t = HEAD + F_F2T;

    for (int i = tid; i < RR * 64; i += 256)
        s_feat[i] = feat[(size_t)n * RR * 64 + i] * rinv[i >> 6];
    __syncthreads();

    const int o = tid & 127;
    const int rh = tid >> 7;

    float acc[16];
#pragma unroll
    for (int r = 0; r < 16; ++r) acc[r] = b1[o];
    for (int c4 = 0; c4 < 16; ++c4) {
        float w0 = W1t[(c4 * 4 + 0) * 128 + o];
        float w1 = W1t[(c4 * 4 + 1) * 128 + o];
        float w2 = W1t[(c4 * 4 + 2) * 128 + o];
        float w3 = W1t[(c4 * 4 + 3) * 128 + o];
#pragma unroll
        for (int r = 0; r < 16; ++r) {
            float4 f = *reinterpret_cast<const float4*>(&s_feat[(rh * 16 + r) * 64 + c4 * 4]);
            acc[r] += f.x * w0 + f.y * w1 + f.z * w2 + f.w * w3;
        }
    }
#pragma unroll
    for (int r = 0; r < 16; ++r) s_h1[(rh * 16 + r) * 128 + o] = fmaxf(acc[r], 0.f);
    __syncthreads();

#pragma unroll
    for (int r = 0; r < 16; ++r) acc[r] = b2[o];
    for (int c4 = 0; c4 < 32; ++c4) {
        float w0 = W2t[(c4 * 4 + 0) * 128 + o];
        float w1 = W2t[(c4 * 4 + 1) * 128 + o];
        float w2 = W2t[(c4 * 4 + 2) * 128 + o];
        float w3 = W2t[(c4 * 4 + 3) * 128 + o];
#pragma unroll
        for (int r = 0; r < 16; ++r) {
            float4 f = *reinterpret_cast<const float4*>(&s_h1[(rh * 16 + r) * 128 + c4 * 4]);
            acc[r] += f.x * w0 + f.y * w1 + f.z * w2 + f.w * w3;
        }
    }
    float ps = 0.f;
#pragma unroll
    for (int r = 0; r < 16; ++r) ps += fmaxf(acc[r], 0.f);
    s_s[rh * 128 + o] = ps;
    __syncthreads();
    if (tid < 128) s_sf[tid] = s_s[tid] + s_s[128 + tid];
    __syncthreads();

    {
        float a = bf1[tid];
        for (int c4 = 0; c4 < 32; ++c4) {
            float4 f = *reinterpret_cast<const float4*>(&s_sf[c4 * 4]);
            a += f.x * F1t[(c4 * 4 + 0) * 256 + tid];
            a += f.y * F1t[(c4 * 4 + 1) * 256 + tid];
            a += f.z * F1t[(c4 * 4 + 2) * 256 + tid];
            a += f.w * F1t[(c4 * 4 + 3) * 256 + tid];
        }
        s_t1[tid] = fmaxf(a, 0.f);
    }
    __syncthreads();

    {
        float a = bf2[tid];
        for (int c4 = 0; c4 < 64; ++c4) {
            float4 f = *reinterpret_cast<const float4*>(&s_t1[c4 * 4]);
            a += f.x * F2t[(c4 * 4 + 0) * 256 + tid];
            a += f.y * F2t[(c4 * 4 + 1) * 256 + tid];
            a += f.z * F2t[(c4 * 4 + 2) * 256 + tid];
            a += f.w * F2t[(c4 * 4 + 3) * 256 + tid];
        }
        outp[(size_t)n * 256 + tid] = a;
    }
}

// ---------------------------------------------------------------------------
extern "C" void kernel_launch(void* const* d_in, const int* in_sizes, int n_in,
                              void* d_out, int out_size, void* d_ws, size_t ws_size,
                              hipStream_t stream)
{
    const int* pos = (const int*)d_in[0];
    const float* rt = (const float*)d_in[1];
    const float* emb = (const float*)d_in[2];
    const float* w1 = (const float*)d_in[3];
    const float* bc1 = (const float*)d_in[4];
    const float* w2 = (const float*)d_in[5];
    const float* bc2 = (const float*)d_in[6];
    const float* w3 = (const float*)d_in[7];
    const float* bc3 = (const float*)d_in[8];
    const float* wr1 = (const float*)d_in[9];
    const float* br1 = (const float*)d_in[10];
    const float* wr2 = (const float*)d_in[11];
    const float* br2 = (const float*)d_in[12];
    const float* wf1 = (const float*)d_in[13];
    const float* bf1 = (const float*)d_in[14];
    const float* wf2 = (const float*)d_in[15];
    const float* bf2 = (const float*)d_in[16];
    float* out = (float*)d_out;
    char* ws = (char*)d_ws;

    // one merged prep: 225280 weight ids + 8192 imask ids + 32 room ids
    prep_all<<<913, 256, 0, stream>>>(w1, w2, w3, wr1, wr2, wf1, wf2, rt, pos, ws);

    const short* WALL = (const short*)(ws + B_W1F);
    const unsigned long long* RMASK = (const unsigned long long*)(ws + B_RAUX);
    const float* RINV = (const float*)(ws + B_RINV);
    float* HEAD = (float*)(ws + B_HEAD);
    float* FEAT = (float*)(ws + B_FEAT);
    unsigned* IMSK = (unsigned*)(ws + B_IMSK);

    fused_conv<<<dim3(RR, NB), 256, 0, stream>>>(IMSK, rt, emb, WALL,
                                                 bc1, bc2, bc3, pos, RMASK, FEAT);

    mlp_head<<<NB, 256, 0, stream>>>(FEAT, HEAD, RINV, br1, br2, bf1, bf2, out);
}

// Round 10
// 298.878 us; speedup vs baseline: 1.0502x; 1.0502x over previous
//
#include <hip/hip_runtime.h>
#include <hip/hip_bf16.h>
#include <cstddef>

// Problem constants
#define NB 256   // batch
#define RR 32    // rooms
#define WW 8     // room width
#define HH 6     // room height
#define MXY 72   // map extent
#define EMB 6
#define CIN1 16  // 9 + 1 + 6

typedef __bf16 bf16x8 __attribute__((ext_vector_type(8)));
typedef float floatx4 __attribute__((ext_vector_type(4)));

// --- Workspace layout (byte offsets) ---------------------------------------
// Conv weights packed per-kstep (2KB per kstep per ntile-group layout):
//   W1F: 13+1 ksteps [0,57344) ; W2F: 18 [57344,131072) ; W3F: 18 [131072,..)
static const size_t B_W1F  = 0;
static const size_t B_W2F  = 57344;
static const size_t B_W3F  = 131072;
static const size_t B_RAUX = 204800;    // room masks (32 u64)
static const size_t B_RINV = 205056;    // 1/room_size (32 f32)
static const size_t B_HEAD = 205312;    // fp32 head weights, 122880 floats
static const size_t F_WR1T = 0;         // (64,128)
static const size_t F_WR2T = 8192;      // (128,128)
static const size_t F_F1T  = 24576;     // (128,256)
static const size_t F_F2T  = 57344;     // (256,256)
static const size_t B_FEAT = 696832;    // (256,32,64) f32 = 2 MB
static const size_t B_IMSK = 2793984;   // (256,32) u32 intersect masks (32 KB)
static const size_t B_SSUM = 2826752;   // (256,128) f32 room-sum partials (128 KB)

__device__ inline short f2b(float f) {
    unsigned u = __builtin_bit_cast(unsigned, f);
    unsigned r = (u + 0x7fffu + ((u >> 16) & 1u)) >> 16;
    return (short)r;
}

// ---------------------------------------------------------------------------
// ONE merged prep kernel. Disjoint index ranges:
//   [0, 225280)          weights -> bf16 B-frag order + head transposes
//   [225280, 233472)     per-(sample,room) 32-bit intersect masks
//   [233472, 233504)     room footprint bitmasks + 1/room_size
//   [233504, 266272)     zero SSUM (256x128 f32)
// Fragment order: [kk][ntile][lane][j] ; virtual k = kk*32 + (lane>>4)*8 + j
// oc = ntile*16 + (lane&15).
// conv1: (tap,ci) natural. conv2/3: position cp -> channel (cp>>2)+(cp&3)*16
// (paired-channel layout Y1/Y2 are written in).
// ---------------------------------------------------------------------------
__global__ void prep_all(const float* __restrict__ w1, const float* __restrict__ w2,
                         const float* __restrict__ w3, const float* __restrict__ wr1,
                         const float* __restrict__ wr2, const float* __restrict__ wf1,
                         const float* __restrict__ wf2, const float* __restrict__ rt,
                         const int* __restrict__ pos, char* __restrict__ ws)
{
    short* W1F = (short*)(ws + B_W1F);
    short* W2F = (short*)(ws + B_W2F);
    short* W3F = (short*)(ws + B_W3F);
    float* HEAD = (float*)(ws + B_HEAD);

    int idx = blockIdx.x * 256 + threadIdx.x;
    if (idx < 28672) {  // conv1: 14 ksteps (padded), CIN=16, taps 0..24 real
        int j = idx & 7, lane = (idx >> 3) & 63, nt = (idx >> 9) & 3, kk = idx >> 11;
        int k = kk * 32 + (lane >> 4) * 8 + j;
        int oc = nt * 16 + (lane & 15);
        int tap = k >> 4, ci = k & 15;
        float v = (tap < 25) ? w1[(oc * 16 + ci) * 25 + tap] : 0.f;
        W1F[idx] = f2b(v);
        return;
    }
    idx -= 28672;
    if (idx < 36864) {  // conv2: 18 ksteps, CIN=64, 9 taps, permuted ci
        int j = idx & 7, lane = (idx >> 3) & 63, nt = (idx >> 9) & 3, kk = idx >> 11;
        int k = kk * 32 + (lane >> 4) * 8 + j;
        int oc = nt * 16 + (lane & 15);
        int tap = k >> 6, cp = k & 63;
        int ci = (cp >> 2) + (cp & 3) * 16;
        W2F[idx] = f2b(w2[(oc * 64 + ci) * 9 + tap]);
        return;
    }
    idx -= 36864;
    if (idx < 36864) {  // conv3, permuted ci
        int j = idx & 7, lane = (idx >> 3) & 63, nt = (idx >> 9) & 3, kk = idx >> 11;
        int k = kk * 32 + (lane >> 4) * 8 + j;
        int oc = nt * 16 + (lane & 15);
        int tap = k >> 6, cp = k & 63;
        int ci = (cp >> 2) + (cp & 3) * 16;
        W3F[idx] = f2b(w3[(oc * 64 + ci) * 9 + tap]);
        return;
    }
    idx -= 36864;
    if (idx < 8192)  { int o = idx & 127, c = idx >> 7; HEAD[F_WR1T + idx] = wr1[o * 64 + c]; return; }
    idx -= 8192;
    if (idx < 16384) { int o = idx & 127, c = idx >> 7; HEAD[F_WR2T + idx] = wr2[o * 128 + c]; return; }
    idx -= 16384;
    if (idx < 32768) { int o = idx & 255, c = idx >> 8; HEAD[F_F1T + idx] = wf1[o * 128 + c]; return; }
    idx -= 32768;
    if (idx < 65536) { int o = idx & 255, c = idx >> 8; HEAD[F_F2T + idx] = wf2[o * 256 + c]; return; }
    idx -= 65536;
    if (idx < 8192) {  // intersect masks: rooms touching the 16x14 X halo tile
        const int n = idx >> 5, r0 = idx & 31;
        const int px0 = pos[(n * RR + r0) * 2 + 0];
        const int py0 = pos[(n * RR + r0) * 2 + 1];
        unsigned m = 0;
        for (int r = 0; r < RR; ++r) {
            int rpx = pos[(n * RR + r) * 2 + 0];
            int rpy = pos[(n * RR + r) * 2 + 1];
            if (rpx >= px0 - 11 && rpx <= px0 + 11 && rpy >= py0 - 9 && rpy <= py0 + 9)
                m |= 1u << r;
        }
        ((unsigned*)(ws + B_IMSK))[n * RR + r0] = m;
        return;
    }
    idx -= 8192;
    if (idx < RR) {  // room footprint bitmasks (48 bits) + 1/room_size
        unsigned long long m = 0ull;
        int cnt = 0;
        for (int j = 0; j < WW * HH; ++j)
            if (rt[idx * 9 * 48 + j] != 0.f) { m |= (1ull << j); ++cnt; }
        ((unsigned long long*)(ws + B_RAUX))[idx] = m;
        ((float*)(ws + B_RINV))[idx] = 1.f / (float)cnt;
        return;
    }
    idx -= RR;
    if (idx < NB * 128) ((float*)(ws + B_SSUM))[idx] = 0.f;  // zero SSUM
}

// ---------------------------------------------------------------------------
// ROUND-10 FUSED CONV CHAIN == round-8's proven config (217.6us).
// Round-9's (256,5) push REGRESSED (229us): the tighter budget squeezed arch
// VGPRs 56->48 and re-introduced a small spill (WRITE 2->7MB); occupancy
// 43->52% bought nothing -> the conv is NOT occupancy-starved at 4 blk/CU.
// (256,4) is the empirical optimum across 7 structural probes.
// ---------------------------------------------------------------------------
__global__ __launch_bounds__(256, 4) void fused_conv(
    const unsigned* __restrict__ imask, const float* __restrict__ rt,
    const float* __restrict__ emb, const short* __restrict__ wAll,
    const float* __restrict__ bc1, const float* __restrict__ bc2,
    const float* __restrict__ bc3, const int* __restrict__ pos,
    const unsigned long long* __restrict__ rmask, float* __restrict__ feat)
{
    __shared__ __align__(16) short s_Y1[120 * 72];  // 17280 B, paired-channel
    __shared__ __align__(16) short s_u[80 * 72];    // X[224][24] then Y2[80][72]
    __shared__ float s_feat[64];

    const int tid = threadIdx.x;
    const int lane = tid & 63;
    const int wv = tid >> 6;
    const int ml = lane & 15;
    const int q = lane >> 4;
    const int room = blockIdx.x;
    const int n = blockIdx.y;

    const int px = pos[(n * RR + room) * 2 + 0];
    const int py = pos[(n * RR + room) * 2 + 1];

    const short* W1F = wAll;
    const short* W2F = wAll + B_W2F / 2;
    const short* W3F = wAll + B_W3F / 2;

    bf16x8 Bb[2][4];
    auto load_k = [&](const short* wF, int kk, bf16x8* dst) {
        const short* src = wF + (size_t)kk * 2048;
#pragma unroll
        for (int j2 = 0; j2 < 4; ++j2)
            dst[j2] = *reinterpret_cast<const bf16x8*>(src + (j2 * 64 + lane) * 8);
    };

    load_k(W1F, 0, Bb[0]);

    // ---- build X tile in-kernel: threads 0..223, one 16-channel pixel ----
    {
        const unsigned mk0 = imask[n * RR + room];  // uniform
        if (tid < 224) {
            const int row = tid / 14, col = tid - (tid / 14) * 14;
            const int gx = px - 4 + row, gy = py - 4 + col;
            float a[16];
#pragma unroll
            for (int c = 0; c < 16; ++c) a[c] = 0.f;
            a[9] = ((unsigned)gx < (unsigned)MXY && (unsigned)gy < (unsigned)MXY) ? 1.f : 0.f;

            unsigned mm = mk0;
            while (mm) {
                const int r = __builtin_ctz(mm);
                mm &= mm - 1;
                const int rpx = pos[(n * RR + r) * 2 + 0];  // uniform -> s_load
                const int rpy = pos[(n * RR + r) * 2 + 1];
                const int w = gx - rpx, h = gy - rpy;
                if ((unsigned)w < (unsigned)WW && (unsigned)h < (unsigned)HH) {
                    const int j = w * HH + h;
                    const float* rr = rt + r * 9 * 48;
#pragma unroll
                    for (int c = 0; c < 9; ++c) a[c] += rr[c * 48 + j];
                    const float mv = rr[j];  // channel 0 = room_map
#pragma unroll
                    for (int e = 0; e < EMB; ++e) a[10 + e] += emb[r * EMB + e] * mv;
                }
            }
            short o[16];
#pragma unroll
            for (int c = 0; c < 16; ++c) o[c] = f2b(a[c]);
            *reinterpret_cast<uint4*>(&s_u[tid * 24 + 0]) = *reinterpret_cast<uint4*>(o);
            *reinterpret_cast<uint4*>(&s_u[tid * 24 + 8]) = *reinterpret_cast<uint4*>(o + 8);
        }
    }
    __syncthreads();  // barrier 1: X staged

    // ================= conv1: 5x5, X(16ch) -> Y1 12x10x64 =================
    {
        int prow[2], pcol[2];
#pragma unroll
        for (int i = 0; i < 2; ++i) {
            int p = wv * 32 + i * 16 + ml;
            if (p > 119) p = 119;  // pad px: duplicate compute, discarded
            prow[i] = p / 10; pcol[i] = p - prow[i] * 10;
        }
        floatx4 acc1[2][4] = {};

#pragma unroll
        for (int kk = 0; kk < 13; ++kk) {  // taps 0..25 (25 zero-padded)
            if (kk < 12) load_k(W1F, kk + 1, Bb[(kk + 1) & 1]);
            else         load_k(W2F, 0, Bb[1]);  // chain prefetch into conv2
            int tap = kk * 2 + (q >> 1);
            if (tap > 24) tap = 24;  // k-slots past tap24 have zero weights
            int chb = (q & 1) * 8;
            int dx = tap / 5, dy = tap - dx * 5;
            __builtin_amdgcn_s_setprio(1);
#pragma unroll
            for (int i = 0; i < 2; ++i) {
                bf16x8 A = *reinterpret_cast<const bf16x8*>(
                    &s_u[((prow[i] + dx) * 14 + (pcol[i] + dy)) * 24 + chb]);
#pragma unroll
                for (int j2 = 0; j2 < 4; ++j2)
                    acc1[i][j2] = __builtin_amdgcn_mfma_f32_16x16x32_bf16(
                        A, Bb[kk & 1][j2], acc1[i][j2], 0, 0, 0);
            }
            __builtin_amdgcn_s_setprio(0);
        }
        // epilogue: bias + relu, b64 paired-channel stores
        float b4[4];
#pragma unroll
        for (int j2 = 0; j2 < 4; ++j2) b4[j2] = bc1[j2 * 16 + ml];
#pragma unroll
        for (int i = 0; i < 2; ++i)
#pragma unroll
            for (int r = 0; r < 4; ++r) {
                int p = wv * 32 + i * 16 + q * 4 + r;
                if (p < 120) {
                    unsigned lo = (unsigned)(unsigned short)f2b(fmaxf(acc1[i][0][r] + b4[0], 0.f))
                                | ((unsigned)(unsigned short)f2b(fmaxf(acc1[i][1][r] + b4[1], 0.f)) << 16);
                    unsigned hi = (unsigned)(unsigned short)f2b(fmaxf(acc1[i][2][r] + b4[2], 0.f))
                                | ((unsigned)(unsigned short)f2b(fmaxf(acc1[i][3][r] + b4[3], 0.f)) << 16);
                    *reinterpret_cast<uint2*>(&s_Y1[p * 72 + ml * 4]) = make_uint2(lo, hi);
                }
            }
    }
    __syncthreads();  // barrier 2: Y1 complete; X dead

    // ===== conv2: 3x3, Y1 -> Y2 10x8x64 (tiles 0-3 owned, tile 4 n-split) ==
    {
        int prowA, pcolA, prowB, pcolB;
        {
            int p0 = wv * 16 + ml; prowA = p0 >> 3; pcolA = p0 & 7;
            int p1 = 64 + ml;      prowB = p1 >> 3; pcolB = p1 & 7;
        }
        floatx4 acc2[4] = {};
        floatx4 acc2s = {};

#pragma unroll
        for (int kk = 0; kk < 18; ++kk) {
            if (kk < 17) load_k(W2F, kk + 1, Bb[kk & 1]);
            else         load_k(W3F, 0, Bb[1]);  // chain prefetch into conv3
            // n-split tile's B frag: direct per-kstep load (L1-resident),
            // wave-uniform base (rule #20 safe), no ping-pong liveness.
            bf16x8 B4 = *reinterpret_cast<const bf16x8*>(
                W2F + (size_t)kk * 2048 + (wv * 64 + lane) * 8);
            const int tap = kk >> 1;
            const int chb = (kk & 1) * 32 + q * 8;
            const int dx = tap / 3, dy = tap - (tap / 3) * 3;
            bf16x8 A0 = *reinterpret_cast<const bf16x8*>(
                &s_Y1[((prowA + dx) * 10 + (pcolA + dy)) * 72 + chb]);
            bf16x8 A4 = *reinterpret_cast<const bf16x8*>(
                &s_Y1[((prowB + dx) * 10 + (pcolB + dy)) * 72 + chb]);
            __builtin_amdgcn_s_setprio(1);
#pragma unroll
            for (int j2 = 0; j2 < 4; ++j2)
                acc2[j2] = __builtin_amdgcn_mfma_f32_16x16x32_bf16(A0, Bb[(kk + 1) & 1][j2], acc2[j2], 0, 0, 0);
            acc2s = __builtin_amdgcn_mfma_f32_16x16x32_bf16(A4, B4, acc2s, 0, 0, 0);
            __builtin_amdgcn_s_setprio(0);
        }
        // epilogue into s_u (X dead): own tile b64, shared tile scalar
        float b4[4];
#pragma unroll
        for (int j2 = 0; j2 < 4; ++j2) b4[j2] = bc2[j2 * 16 + ml];
#pragma unroll
        for (int r = 0; r < 4; ++r) {
            int p = wv * 16 + q * 4 + r;
            unsigned lo = (unsigned)(unsigned short)f2b(fmaxf(acc2[0][r] + b4[0], 0.f))
                        | ((unsigned)(unsigned short)f2b(fmaxf(acc2[1][r] + b4[1], 0.f)) << 16);
            unsigned hi = (unsigned)(unsigned short)f2b(fmaxf(acc2[2][r] + b4[2], 0.f))
                        | ((unsigned)(unsigned short)f2b(fmaxf(acc2[3][r] + b4[3], 0.f)) << 16);
            *reinterpret_cast<uint2*>(&s_u[p * 72 + ml * 4]) = make_uint2(lo, hi);
        }
        {
            float bt = bc2[wv * 16 + ml];
#pragma unroll
            for (int r = 0; r < 4; ++r) {
                int p = 64 + q * 4 + r;
                s_u[p * 72 + ml * 4 + wv] = f2b(fmaxf(acc2s[r] + bt, 0.f));
            }
        }
        if (tid < 64) s_feat[tid] = 0.f;
    }
    __syncthreads();  // barrier 3: Y2 complete

    // ====== conv3: 3x3, Y2 -> 8x6 masked room-sum (waves 0-2) ======
    if (wv < 3) {
        int p0 = wv * 16 + ml;
        int row3 = p0 / 6, col3 = p0 - (p0 / 6) * 6;
        floatx4 acc3[4] = {};

#pragma unroll
        for (int kk = 0; kk < 18; ++kk) {
            if (kk < 17) load_k(W3F, kk + 1, Bb[kk & 1]);
            const int tap = kk >> 1;
            const int chb = (kk & 1) * 32 + q * 8;
            const int dx = tap / 3, dy = tap - (tap / 3) * 3;
            bf16x8 A = *reinterpret_cast<const bf16x8*>(
                &s_u[((row3 + dx) * 8 + (col3 + dy)) * 72 + chb]);
            __builtin_amdgcn_s_setprio(1);
#pragma unroll
            for (int j2 = 0; j2 < 4; ++j2)
                acc3[j2] = __builtin_amdgcn_mfma_f32_16x16x32_bf16(A, Bb[(kk + 1) & 1][j2], acc3[j2], 0, 0, 0);
            __builtin_amdgcn_s_setprio(0);
        }
        float b4[4];
#pragma unroll
        for (int j2 = 0; j2 < 4; ++j2) b4[j2] = bc3[j2 * 16 + ml];
        float part[4] = {0.f, 0.f, 0.f, 0.f};
        const unsigned long long mk = rmask[room];
#pragma unroll
        for (int r = 0; r < 4; ++r) {
            int p = wv * 16 + q * 4 + r;  // == w*6+h == mask bit index
            if ((mk >> p) & 1ull) {
#pragma unroll
                for (int j2 = 0; j2 < 4; ++j2)
                    part[j2] += fmaxf(acc3[j2][r] + b4[j2], 0.f);
            }
        }
#pragma unroll
        for (int j2 = 0; j2 < 4; ++j2) {
            part[j2] += __shfl_xor(part[j2], 16);
            part[j2] += __shfl_xor(part[j2], 32);
        }
        if (q == 0) {
#pragma unroll
            for (int j2 = 0; j2 < 4; ++j2)
                atomicAdd(&s_feat[j2 * 16 + ml], part[j2]);  // 3 contenders
        }
    }
    __syncthreads();  // barrier 4
    if (tid < 64)
        feat[((size_t)n * RR + room) * 64 + tid] = s_feat[tid];
}

// ---------------------------------------------------------------------------
// ROUND-10 head split. Old mlp_head ran 256 blocks = 1 wave/SIMD: zero TLP,
// every L2 weight-load latency exposed (~50us). head_rooms: 4 blocks/sample
// (1024 total, 4 blk/CU) each does the room MLP (64->128->128) for 8 rooms
// and atomicAdds its 128-float partial room-sum into SSUM. head_fc does
// fc1+fc2 per sample from SSUM (trivial).
// ---------------------------------------------------------------------------
__global__ __launch_bounds__(256) void head_rooms(const float* __restrict__ feat,
                                                  const float* __restrict__ HEAD,
                                                  const float* __restrict__ rinv,
                                                  const float* __restrict__ b1,
                                                  const float* __restrict__ b2,
                                                  float* __restrict__ ssum)
{
    __shared__ __align__(16) float s_feat[8 * 64];
    __shared__ __align__(16) float s_h1[8 * 128];
    __shared__ __align__(16) float s_s[2 * 128];

    const int qr = blockIdx.x;   // 0..3 -> rooms qr*8 .. qr*8+7
    const int n = blockIdx.y;
    const int tid = threadIdx.x;
    const float* W1t = HEAD + F_WR1T;
    const float* W2t = HEAD + F_WR2T;

    for (int i = tid; i < 8 * 64; i += 256)
        s_feat[i] = feat[(size_t)n * RR * 64 + qr * 512 + i] * rinv[qr * 8 + (i >> 6)];
    __syncthreads();

    const int o = tid & 127;
    const int rh = tid >> 7;     // rooms rh*4 .. rh*4+3 (local)

    float acc[4];
#pragma unroll
    for (int r = 0; r < 4; ++r) acc[r] = b1[o];
    for (int c4 = 0; c4 < 16; ++c4) {
        float w0 = W1t[(c4 * 4 + 0) * 128 + o];
        float w1 = W1t[(c4 * 4 + 1) * 128 + o];
        float w2 = W1t[(c4 * 4 + 2) * 128 + o];
        float w3 = W1t[(c4 * 4 + 3) * 128 + o];
#pragma unroll
        for (int r = 0; r < 4; ++r) {
            float4 f = *reinterpret_cast<const float4*>(&s_feat[(rh * 4 + r) * 64 + c4 * 4]);
            acc[r] += f.x * w0 + f.y * w1 + f.z * w2 + f.w * w3;
        }
    }
#pragma unroll
    for (int r = 0; r < 4; ++r) s_h1[(rh * 4 + r) * 128 + o] = fmaxf(acc[r], 0.f);
    __syncthreads();

#pragma unroll
    for (int r = 0; r < 4; ++r) acc[r] = b2[o];
    for (int c4 = 0; c4 < 32; ++c4) {
        float w0 = W2t[(c4 * 4 + 0) * 128 + o];
        float w1 = W2t[(c4 * 4 + 1) * 128 + o];
        float w2 = W2t[(c4 * 4 + 2) * 128 + o];
        float w3 = W2t[(c4 * 4 + 3) * 128 + o];
#pragma unroll
        for (int r = 0; r < 4; ++r) {
            float4 f = *reinterpret_cast<const float4*>(&s_h1[(rh * 4 + r) * 128 + c4 * 4]);
            acc[r] += f.x * w0 + f.y * w1 + f.z * w2 + f.w * w3;
        }
    }
    float ps = 0.f;
#pragma unroll
    for (int r = 0; r < 4; ++r) ps += fmaxf(acc[r], 0.f);
    s_s[rh * 128 + o] = ps;
    __syncthreads();
    if (tid < 128)
        atomicAdd(&ssum[(size_t)n * 128 + tid], s_s[tid] + s_s[128 + tid]);
}

__global__ __launch_bounds__(256) void head_fc(const float* __restrict__ ssum,
                                               const float* __restrict__ HEAD,
                                               const float* __restrict__ bf1,
                                               const float* __restrict__ bf2,
                                               float* __restrict__ outp)
{
    __shared__ __align__(16) float s_sf[128];
    __shared__ __align__(16) float s_t1[256];

    const int n = blockIdx.x;
    const int tid = threadIdx.x;
    const float* F1t = HEAD + F_F1T;
    const float* F2t = HEAD + F_F2T;

    if (tid < 128) s_sf[tid] = ssum[(size_t)n * 128 + tid];
    __syncthreads();

    {
        float a = bf1[tid];
#pragma unroll 4
        for (int c4 = 0; c4 < 32; ++c4) {
            float4 f = *reinterpret_cast<const float4*>(&s_sf[c4 * 4]);
            a += f.x * F1t[(c4 * 4 + 0) * 256 + tid];
            a += f.y * F1t[(c4 * 4 + 1) * 256 + tid];
            a += f.z * F1t[(c4 * 4 + 2) * 256 + tid];
            a += f.w * F1t[(c4 * 4 + 3) * 256 + tid];
        }
        s_t1[tid] = fmaxf(a, 0.f);
    }
    __syncthreads();

    {
        float a = bf2[tid];
#pragma unroll 4
        for (int c4 = 0; c4 < 64; ++c4) {
            float4 f = *reinterpret_cast<const float4*>(&s_t1[c4 * 4]);
            a += f.x * F2t[(c4 * 4 + 0) * 256 + tid];
            a += f.y * F2t[(c4 * 4 + 1) * 256 + tid];
            a += f.z * F2t[(c4 * 4 + 2) * 256 + tid];
            a += f.w * F2t[(c4 * 4 + 3) * 256 + tid];
        }
        outp[(size_t)n * 256 + tid] = a;
    }
}

// ---------------------------------------------------------------------------
extern "C" void kernel_launch(void* const* d_in, const int* in_sizes, int n_in,
                              void* d_out, int out_size, void* d_ws, size_t ws_size,
                              hipStream_t stream)
{
    const int* pos = (const int*)d_in[0];
    const float* rt = (const float*)d_in[1];
    const float* emb = (const float*)d_in[2];
    const float* w1 = (const float*)d_in[3];
    const float* bc1 = (const float*)d_in[4];
    const float* w2 = (const float*)d_in[5];
    const float* bc2 = (const float*)d_in[6];
    const float* w3 = (const float*)d_in[7];
    const float* bc3 = (const float*)d_in[8];
    const float* wr1 = (const float*)d_in[9];
    const float* br1 = (const float*)d_in[10];
    const float* wr2 = (const float*)d_in[11];
    const float* br2 = (const float*)d_in[12];
    const float* wf1 = (const float*)d_in[13];
    const float* bf1 = (const float*)d_in[14];
    const float* wf2 = (const float*)d_in[15];
    const float* bf2 = (const float*)d_in[16];
    float* out = (float*)d_out;
    char* ws = (char*)d_ws;

    // merged prep: 225280 weight + 8192 imask + 32 room + 32768 ssum-zero ids
    prep_all<<<1041, 256, 0, stream>>>(w1, w2, w3, wr1, wr2, wf1, wf2, rt, pos, ws);

    const short* WALL = (const short*)(ws + B_W1F);
    const unsigned long long* RMASK = (const unsigned long long*)(ws + B_RAUX);
    const float* RINV = (const float*)(ws + B_RINV);
    float* HEAD = (float*)(ws + B_HEAD);
    float* FEAT = (float*)(ws + B_FEAT);
    unsigned* IMSK = (unsigned*)(ws + B_IMSK);
    float* SSUM = (float*)(ws + B_SSUM);

    fused_conv<<<dim3(RR, NB), 256, 0, stream>>>(IMSK, rt, emb, WALL,
                                                 bc1, bc2, bc3, pos, RMASK, FEAT);

    head_rooms<<<dim3(4, NB), 256, 0, stream>>>(FEAT, HEAD, RINV, br1, br2, SSUM);
    head_fc<<<NB, 256, 0, stream>>>(SSUM, HEAD, bf1, bf2, out);
}